// Round 4
// baseline (454.448 us; speedup 1.0000x reference)
//
#include <hip/hip_runtime.h>

#define TPB 256

// ---------------------------------------------------------------------------
// Per-edge histogram: cnt[c] = in-degree (dup kept), rcnt[r] = out-degree
// (dup kept). 4 edges/thread for independent atomic chains.
// ---------------------------------------------------------------------------
__global__ void count_kernel(const int* __restrict__ edge, int E,
                             int* __restrict__ cnt, int* __restrict__ rcnt) {
    int base = (blockIdx.x * blockDim.x + threadIdx.x) * 4;
    int r[4], c[4];
    int m = E - base; if (m <= 0) return; if (m > 4) m = 4;
    for (int u = 0; u < m; u++) { r[u] = edge[base + u]; c[u] = edge[E + base + u]; }
    for (int u = 0; u < m; u++) {
        atomicAdd(&rcnt[r[u]], 1);
        atomicAdd(&cnt[c[u]], 1);
    }
}

// ---------------------------------------------------------------------------
// Single-block exclusive scans:
//   phase 0: (cnt[i]+1) -> offsets (dst-CSR, self-loop at segment head)
//   phase 1: rcnt[i]    -> roffsets (row-CSR, duplicates kept)
// ---------------------------------------------------------------------------
__global__ void scan_kernel(const int* __restrict__ cnt, const int* __restrict__ rcnt,
                            int* __restrict__ offsets, int* __restrict__ fill,
                            int* __restrict__ csr,
                            int* __restrict__ roffsets, int* __restrict__ rfill,
                            int n) {
    __shared__ int sh[1024];
    __shared__ int carry_sh;
    for (int phase = 0; phase < 2; phase++) {
        if (threadIdx.x == 0) carry_sh = 0;
        __syncthreads();
        int nch = (n + 1023) / 1024;
        for (int ch = 0; ch < nch; ch++) {
            int i = ch * 1024 + (int)threadIdx.x;
            int v = 0;
            if (i < n) v = (phase == 0) ? (cnt[i] + 1) : rcnt[i];
            sh[threadIdx.x] = v;
            __syncthreads();
            for (int off = 1; off < 1024; off <<= 1) {
                int t = (threadIdx.x >= (unsigned)off) ? sh[threadIdx.x - off] : 0;
                __syncthreads();
                sh[threadIdx.x] += t;
                __syncthreads();
            }
            int incl = sh[threadIdx.x] + carry_sh;
            if (i < n) {
                int excl = incl - v;
                if (phase == 0) {
                    offsets[i] = excl;
                    fill[i]    = excl + 1;   // slot 0 of the segment = self loop
                    csr[excl]  = i;          // self-loop src
                } else {
                    roffsets[i] = excl;
                    rfill[i]    = excl;
                }
            }
            __syncthreads();
            if (threadIdx.x == 1023) carry_sh = incl;
            __syncthreads();
        }
        if (threadIdx.x == 0) {
            if (phase == 0) offsets[n] = carry_sh;   // = E + n
            else            roffsets[n] = carry_sh;  // = E
        }
        __syncthreads();
    }
}

// ---------------------------------------------------------------------------
// Scatter into dst-CSR (srcs grouped by dst) and row-CSR (dsts grouped by
// src, duplicates kept). 4 edges/thread.
// ---------------------------------------------------------------------------
__global__ void scatter_kernel(const int* __restrict__ edge, int E,
                               int* __restrict__ fill, int* __restrict__ csr,
                               int* __restrict__ rfill, int* __restrict__ rcsr) {
    int base = (blockIdx.x * blockDim.x + threadIdx.x) * 4;
    int r[4], c[4];
    int m = E - base; if (m <= 0) return; if (m > 4) m = 4;
    for (int u = 0; u < m; u++) { r[u] = edge[base + u]; c[u] = edge[E + base + u]; }
    for (int u = 0; u < m; u++) {
        int p = atomicAdd(&fill[c[u]], 1);
        csr[p] = r[u];
        int q = atomicAdd(&rfill[r[u]], 1);
        rcsr[q] = c[u];
    }
}

// ---------------------------------------------------------------------------
// h = x @ W (per node) + per-head attention logits. Templated so xv[] stays
// in registers and loops fully unroll. W, a_src, a_dst staged in LDS.
// ---------------------------------------------------------------------------
template <int IN, int H>
__global__ void transform_kernel(const float* __restrict__ x, const float* __restrict__ W,
                                 const float* __restrict__ asrc, const float* __restrict__ adst,
                                 int n, float* __restrict__ h, float* __restrict__ es,
                                 float* __restrict__ ed) {
    constexpr int HC = H * 4;
    __shared__ float sW[IN * HC];
    __shared__ float sa[HC];
    __shared__ float sd[HC];
    for (int i = threadIdx.x; i < IN * HC; i += blockDim.x) sW[i] = W[i];
    if (threadIdx.x < HC) { sa[threadIdx.x] = asrc[threadIdx.x]; sd[threadIdx.x] = adst[threadIdx.x]; }
    __syncthreads();
    int node = blockIdx.x * blockDim.x + threadIdx.x;
    if (node >= n) return;
    float xv[IN];
#pragma unroll
    for (int k = 0; k < IN; k++) xv[k] = x[(size_t)node * IN + k];
#pragma unroll
    for (int hd = 0; hd < H; hd++) {
        float e1 = 0.f, e2 = 0.f;
#pragma unroll
        for (int c = 0; c < 4; c++) {
            int o = hd * 4 + c;
            float acc = 0.f;
#pragma unroll
            for (int k = 0; k < IN; k++) acc += xv[k] * sW[k * HC + o];
            h[(size_t)node * HC + o] = acc;
            e1 += acc * sa[o];
            e2 += acc * sd[o];
        }
        es[(size_t)node * H + hd] = e1;
        ed[(size_t)node * H + hd] = e2;
    }
}

// ---------------------------------------------------------------------------
// Segment softmax + aggregation, one thread per (dst, head), ONE pass using
// online softmax (running max + rescale). Epilogue: /denom, +bias, relu.
// ---------------------------------------------------------------------------
template <int H>
__global__ void aggregate_kernel(const int* __restrict__ offsets, const int* __restrict__ csr,
                                 const float* __restrict__ h, const float* __restrict__ es,
                                 const float* __restrict__ ed, const float* __restrict__ bias,
                                 int n, float* __restrict__ xout) {
    constexpr int HC = H * 4;
    int tid = blockIdx.x * blockDim.x + threadIdx.x;
    if (tid >= n * H) return;
    int node = tid / H;
    int hd   = tid % H;
    int beg = offsets[node], end = offsets[node + 1];
    float edv = ed[(size_t)node * H + hd];
    float m = -1e30f, denom = 0.f;
    float4 acc = make_float4(0.f, 0.f, 0.f, 0.f);
    for (int k = beg; k < end; k++) {
        int s = csr[k];
        float e = es[(size_t)s * H + hd] + edv;
        e = (e > 0.f) ? e : 0.2f * e;
        if (e > m) {
            float sc = __expf(m - e);      // first iter: expf(-huge) = 0
            denom *= sc;
            acc.x *= sc; acc.y *= sc; acc.z *= sc; acc.w *= sc;
            m = e;
        }
        float w = __expf(e - m);
        float4 hv = *(const float4*)&h[(size_t)s * HC + hd * 4];
        denom += w;
        acc.x += w * hv.x;
        acc.y += w * hv.y;
        acc.z += w * hv.z;
        acc.w += w * hv.w;
    }
    float inv = 1.0f / denom;
    float* op = &xout[(size_t)node * HC + hd * 4];
    const float* bp = &bias[hd * 4];
    float v;
    v = acc.x * inv + bp[0]; op[0] = v > 0.f ? v : 0.f;
    v = acc.y * inv + bp[1]; op[1] = v > 0.f ? v : 0.f;
    v = acc.z * inv + bp[2]; op[2] = v > 0.f ? v : 0.f;
    v = acc.w * inv + bp[3]; op[3] = v > 0.f ? v : 0.f;
}

// ---------------------------------------------------------------------------
// Fused scoring epilogue with inline dedup. One thread per node (64/block):
// walk the row segment (duplicates kept), keep distinct cols in an LDS list
// (O(d^2) dup check, avg d=32), accumulate s_i over distinct neighbors.
//   out[i] = (x6[i]·s_i + s_i·lin2_w)/deg_i + x1[i,0]
// Diagonal contributes iff edge (i,i) absent. FSEG=96 covers Poisson(32)
// tails with astronomical margin; >FSEG falls back to global O(d^2).
// ---------------------------------------------------------------------------
#define FSEG 96
__global__ __launch_bounds__(64) void final_kernel(const float* __restrict__ x6,
                             const int* __restrict__ roffsets, const int* __restrict__ rcsr,
                             const float* __restrict__ x1, const float* __restrict__ lw,
                             float* __restrict__ out, int n) {
    __shared__ int seg[64 * (FSEG + 1)];   // stride 97: 2-way LDS aliasing only
    int lane = threadIdx.x;
    int i = blockIdx.x * 64 + lane;
    if (i >= n) return;
    int* my = &seg[lane * (FSEG + 1)];
    int beg = roffsets[i], end = roffsets[i + 1];
    int draw = end - beg;
    const float4* x6v = (const float4*)x6;
    float4 s0 = make_float4(0.f, 0.f, 0.f, 0.f);
    float4 s1 = make_float4(0.f, 0.f, 0.f, 0.f);
    int nd = 0;
    bool selfSet = false;
    if (draw <= FSEG) {
        for (int k = beg; k < end; k++) {
            int c = rcsr[k];
            bool dup = false;
            for (int j = 0; j < nd; j++) if (my[j] == c) { dup = true; break; }
            if (!dup) {
                my[nd++] = c;
                if (c == i) selfSet = true;
                float4 a = x6v[(size_t)c * 2];
                float4 b = x6v[(size_t)c * 2 + 1];
                s0.x += a.x; s0.y += a.y; s0.z += a.z; s0.w += a.w;
                s1.x += b.x; s1.y += b.y; s1.z += b.z; s1.w += b.w;
            }
        }
    } else {
        for (int k = beg; k < end; k++) {          // never expected; correctness net
            int c = rcsr[k];
            bool dup = false;
            for (int j = beg; j < k; j++) if (rcsr[j] == c) { dup = true; break; }
            if (!dup) {
                nd++;
                if (c == i) selfSet = true;
                float4 a = x6v[(size_t)c * 2];
                float4 b = x6v[(size_t)c * 2 + 1];
                s0.x += a.x; s0.y += a.y; s0.z += a.z; s0.w += a.w;
                s1.x += b.x; s1.y += b.y; s1.z += b.z; s1.w += b.w;
            }
        }
    }
    float4 me0 = x6v[(size_t)i * 2];
    float4 me1 = x6v[(size_t)i * 2 + 1];
    if (!selfSet) {
        s0.x += me0.x; s0.y += me0.y; s0.z += me0.z; s0.w += me0.w;
        s1.x += me1.x; s1.y += me1.y; s1.z += me1.z; s1.w += me1.w;
        nd += 1;
    }
    float d = (float)nd;
    float r2 = s0.x * me0.x + s0.y * me0.y + s0.z * me0.z + s0.w * me0.w
             + s1.x * me1.x + s1.y * me1.y + s1.z * me1.z + s1.w * me1.w;
    float gs = s0.x * lw[0] + s0.y * lw[1] + s0.z * lw[2] + s0.w * lw[3]
             + s1.x * lw[4] + s1.y * lw[5] + s1.z * lw[6] + s1.w * lw[7];
    out[i] = (r2 + gs) / d + x1[(size_t)i * 10];
}

static inline size_t align16(size_t x) { return (x + 15) & ~(size_t)15; }

extern "C" void kernel_launch(void* const* d_in, const int* in_sizes, int n_in,
                              void* d_out, int out_size, void* d_ws, size_t ws_size,
                              hipStream_t stream) {
    const float* x1  = (const float*)d_in[0];
    // x2 (d_in[1]) is unused by the reference
    const int*   edge = (const int*)d_in[2];
    const float* W1  = (const float*)d_in[4];
    const float* as1 = (const float*)d_in[5];
    const float* ad1 = (const float*)d_in[6];
    const float* b1  = (const float*)d_in[7];
    const float* W2  = (const float*)d_in[8];
    const float* as2 = (const float*)d_in[9];
    const float* ad2 = (const float*)d_in[10];
    const float* b2  = (const float*)d_in[11];
    const float* W3  = (const float*)d_in[12];
    const float* as3 = (const float*)d_in[13];
    const float* ad3 = (const float*)d_in[14];
    const float* b3  = (const float*)d_in[15];
    const float* lw  = (const float*)d_in[16];
    float* out = (float*)d_out;

    const int n = in_sizes[0] / 10;     // 10000
    const int E = in_sizes[2] / 2;      // 320000

    // ---- workspace layout (16B aligned blocks) ----
    char* p = (char*)d_ws;
    int*   cnt     = (int*)p;   p += align16((size_t)n * 4);
    int*   rcnt    = (int*)p;   p += align16((size_t)n * 4);
    size_t zbytes  = (size_t)(p - (char*)d_ws);      // zero-init region ends here
    int*   fill    = (int*)p;   p += align16((size_t)n * 4);
    int*   rfill   = (int*)p;   p += align16((size_t)n * 4);
    int*   offsets = (int*)p;   p += align16((size_t)(n + 1) * 4);
    int*   roffsets= (int*)p;   p += align16((size_t)(n + 1) * 4);
    int*   csr     = (int*)p;   p += align16((size_t)(E + n) * 4);
    int*   rcsr    = (int*)p;   p += align16((size_t)E * 4);
    float* h1  = (float*)p; p += align16((size_t)n * 32 * 4);
    float* es1 = (float*)p; p += align16((size_t)n * 8 * 4);
    float* ed1 = (float*)p; p += align16((size_t)n * 8 * 4);
    float* x3  = (float*)p; p += align16((size_t)n * 32 * 4);
    float* h2  = (float*)p; p += align16((size_t)n * 16 * 4);
    float* es2 = (float*)p; p += align16((size_t)n * 4 * 4);
    float* ed2 = (float*)p; p += align16((size_t)n * 4 * 4);
    float* x4  = (float*)p; p += align16((size_t)n * 16 * 4);
    float* h3  = (float*)p; p += align16((size_t)n * 8 * 4);
    float* es3 = (float*)p; p += align16((size_t)n * 2 * 4);
    float* ed3 = (float*)p; p += align16((size_t)n * 2 * 4);
    float* x6  = (float*)p; p += align16((size_t)n * 8 * 4);

    hipMemsetAsync(d_ws, 0, zbytes, stream);   // just cnt + rcnt (80 KB)

    int e4bl = (E + TPB * 4 - 1) / (TPB * 4);
    int nbl  = (n + TPB - 1) / TPB;

    count_kernel<<<e4bl, TPB, 0, stream>>>(edge, E, cnt, rcnt);
    scan_kernel<<<1, 1024, 0, stream>>>(cnt, rcnt, offsets, fill, csr, roffsets, rfill, n);
    scatter_kernel<<<e4bl, TPB, 0, stream>>>(edge, E, fill, csr, rfill, rcsr);

    // layer 1: IN=10, H=8
    transform_kernel<10, 8><<<nbl, TPB, 0, stream>>>(x1, W1, as1, ad1, n, h1, es1, ed1);
    aggregate_kernel<8><<<(n * 8 + TPB - 1) / TPB, TPB, 0, stream>>>(
        offsets, csr, h1, es1, ed1, b1, n, x3);

    // layer 2: IN=32, H=4
    transform_kernel<32, 4><<<nbl, TPB, 0, stream>>>(x3, W2, as2, ad2, n, h2, es2, ed2);
    aggregate_kernel<4><<<(n * 4 + TPB - 1) / TPB, TPB, 0, stream>>>(
        offsets, csr, h2, es2, ed2, b2, n, x4);

    // layer 3: IN=16, H=2
    transform_kernel<16, 2><<<nbl, TPB, 0, stream>>>(x4, W3, as3, ad3, n, h3, es3, ed3);
    aggregate_kernel<2><<<(n * 2 + TPB - 1) / TPB, TPB, 0, stream>>>(
        offsets, csr, h3, es3, ed3, b3, n, x6);

    // fused scoring epilogue (row-CSR gather + inline dedup, no atomics)
    final_kernel<<<(n + 63) / 64, 64, 0, stream>>>(x6, roffsets, rcsr, x1, lw, out, n);
}

// Round 5
// 296.397 us; speedup vs baseline: 1.5332x; 1.5332x over previous
//
#include <hip/hip_runtime.h>

#define TPB 256

// ---------------------------------------------------------------------------
// Per-edge histogram: cnt[c] = in-degree (dup kept), rcnt[r] = out-degree
// (dup kept). 4 edges/thread for independent atomic chains.
// ---------------------------------------------------------------------------
__global__ void count_kernel(const int* __restrict__ edge, int E,
                             int* __restrict__ cnt, int* __restrict__ rcnt) {
    int base = (blockIdx.x * blockDim.x + threadIdx.x) * 4;
    int r[4], c[4];
    int m = E - base; if (m <= 0) return; if (m > 4) m = 4;
    for (int u = 0; u < m; u++) { r[u] = edge[base + u]; c[u] = edge[E + base + u]; }
    for (int u = 0; u < m; u++) {
        atomicAdd(&rcnt[r[u]], 1);
        atomicAdd(&cnt[c[u]], 1);
    }
}

// ---------------------------------------------------------------------------
// Single-block exclusive scans:
//   phase 0: (cnt[i]+1) -> offsets (dst-CSR, self-loop at segment head)
//   phase 1: rcnt[i]    -> roffsets (row-CSR, duplicates kept)
// ---------------------------------------------------------------------------
__global__ void scan_kernel(const int* __restrict__ cnt, const int* __restrict__ rcnt,
                            int* __restrict__ offsets, int* __restrict__ fill,
                            int* __restrict__ csr,
                            int* __restrict__ roffsets, int* __restrict__ rfill,
                            int n) {
    __shared__ int sh[1024];
    __shared__ int carry_sh;
    for (int phase = 0; phase < 2; phase++) {
        if (threadIdx.x == 0) carry_sh = 0;
        __syncthreads();
        int nch = (n + 1023) / 1024;
        for (int ch = 0; ch < nch; ch++) {
            int i = ch * 1024 + (int)threadIdx.x;
            int v = 0;
            if (i < n) v = (phase == 0) ? (cnt[i] + 1) : rcnt[i];
            sh[threadIdx.x] = v;
            __syncthreads();
            for (int off = 1; off < 1024; off <<= 1) {
                int t = (threadIdx.x >= (unsigned)off) ? sh[threadIdx.x - off] : 0;
                __syncthreads();
                sh[threadIdx.x] += t;
                __syncthreads();
            }
            int incl = sh[threadIdx.x] + carry_sh;
            if (i < n) {
                int excl = incl - v;
                if (phase == 0) {
                    offsets[i] = excl;
                    fill[i]    = excl + 1;   // slot 0 of the segment = self loop
                    csr[excl]  = i;          // self-loop src
                } else {
                    roffsets[i] = excl;
                    rfill[i]    = excl;
                }
            }
            __syncthreads();
            if (threadIdx.x == 1023) carry_sh = incl;
            __syncthreads();
        }
        if (threadIdx.x == 0) {
            if (phase == 0) offsets[n] = carry_sh;   // = E + n
            else            roffsets[n] = carry_sh;  // = E
        }
        __syncthreads();
    }
}

// ---------------------------------------------------------------------------
// Scatter into dst-CSR (srcs grouped by dst) and row-CSR (dsts grouped by
// src, duplicates kept). 4 edges/thread.
// ---------------------------------------------------------------------------
__global__ void scatter_kernel(const int* __restrict__ edge, int E,
                               int* __restrict__ fill, int* __restrict__ csr,
                               int* __restrict__ rfill, int* __restrict__ rcsr) {
    int base = (blockIdx.x * blockDim.x + threadIdx.x) * 4;
    int r[4], c[4];
    int m = E - base; if (m <= 0) return; if (m > 4) m = 4;
    for (int u = 0; u < m; u++) { r[u] = edge[base + u]; c[u] = edge[E + base + u]; }
    for (int u = 0; u < m; u++) {
        int p = atomicAdd(&fill[c[u]], 1);
        csr[p] = r[u];
        int q = atomicAdd(&rfill[r[u]], 1);
        rcsr[q] = c[u];
    }
}

// ---------------------------------------------------------------------------
// h = x @ W (per node) + per-head attention logits. Templated so xv[] stays
// in registers and loops fully unroll. W, a_src, a_dst staged in LDS.
// ---------------------------------------------------------------------------
template <int IN, int H>
__global__ void transform_kernel(const float* __restrict__ x, const float* __restrict__ W,
                                 const float* __restrict__ asrc, const float* __restrict__ adst,
                                 int n, float* __restrict__ h, float* __restrict__ es,
                                 float* __restrict__ ed) {
    constexpr int HC = H * 4;
    __shared__ float sW[IN * HC];
    __shared__ float sa[HC];
    __shared__ float sd[HC];
    for (int i = threadIdx.x; i < IN * HC; i += blockDim.x) sW[i] = W[i];
    if (threadIdx.x < HC) { sa[threadIdx.x] = asrc[threadIdx.x]; sd[threadIdx.x] = adst[threadIdx.x]; }
    __syncthreads();
    int node = blockIdx.x * blockDim.x + threadIdx.x;
    if (node >= n) return;
    float xv[IN];
#pragma unroll
    for (int k = 0; k < IN; k++) xv[k] = x[(size_t)node * IN + k];
#pragma unroll
    for (int hd = 0; hd < H; hd++) {
        float e1 = 0.f, e2 = 0.f;
#pragma unroll
        for (int c = 0; c < 4; c++) {
            int o = hd * 4 + c;
            float acc = 0.f;
#pragma unroll
            for (int k = 0; k < IN; k++) acc += xv[k] * sW[k * HC + o];
            h[(size_t)node * HC + o] = acc;
            e1 += acc * sa[o];
            e2 += acc * sd[o];
        }
        es[(size_t)node * H + hd] = e1;
        ed[(size_t)node * H + hd] = e2;
    }
}

// ---------------------------------------------------------------------------
// Segment softmax + aggregation, one thread per (dst, head), ONE pass using
// online softmax (running max + rescale). Epilogue: /denom, +bias, relu.
// ---------------------------------------------------------------------------
template <int H>
__global__ void aggregate_kernel(const int* __restrict__ offsets, const int* __restrict__ csr,
                                 const float* __restrict__ h, const float* __restrict__ es,
                                 const float* __restrict__ ed, const float* __restrict__ bias,
                                 int n, float* __restrict__ xout) {
    constexpr int HC = H * 4;
    int tid = blockIdx.x * blockDim.x + threadIdx.x;
    if (tid >= n * H) return;
    int node = tid / H;
    int hd   = tid % H;
    int beg = offsets[node], end = offsets[node + 1];
    float edv = ed[(size_t)node * H + hd];
    float m = -1e30f, denom = 0.f;
    float4 acc = make_float4(0.f, 0.f, 0.f, 0.f);
    for (int k = beg; k < end; k++) {
        int s = csr[k];
        float e = es[(size_t)s * H + hd] + edv;
        e = (e > 0.f) ? e : 0.2f * e;
        if (e > m) {
            float sc = __expf(m - e);      // first iter: expf(-huge) = 0
            denom *= sc;
            acc.x *= sc; acc.y *= sc; acc.z *= sc; acc.w *= sc;
            m = e;
        }
        float w = __expf(e - m);
        float4 hv = *(const float4*)&h[(size_t)s * HC + hd * 4];
        denom += w;
        acc.x += w * hv.x;
        acc.y += w * hv.y;
        acc.z += w * hv.z;
        acc.w += w * hv.w;
    }
    float inv = 1.0f / denom;
    float* op = &xout[(size_t)node * HC + hd * 4];
    const float* bp = &bias[hd * 4];
    float v;
    v = acc.x * inv + bp[0]; op[0] = v > 0.f ? v : 0.f;
    v = acc.y * inv + bp[1]; op[1] = v > 0.f ? v : 0.f;
    v = acc.z * inv + bp[2]; op[2] = v > 0.f ? v : 0.f;
    v = acc.w * inv + bp[3]; op[3] = v > 0.f ? v : 0.f;
}

// ---------------------------------------------------------------------------
// Fused scoring epilogue, ONE WAVE PER NODE (wave-parallel dedup).
// Row segment (duplicates kept): lane l holds element l; first-occurrence
// test via uniform __shfl broadcasts (d<=64 fast path, ~d iterations of
// 3 VALU ops, no LDS/barrier). Winner lanes gather x6[c] (L2-resident),
// butterfly-reduce 8 channels + distinct count. d>64: per-lane global scan
// fallback (astronomically rare at Poisson(32); correctness net).
//   out[i] = (x6[i]·s_i + s_i·lin2_w)/deg_i + x1[i,0]
// Diagonal contributes iff edge (i,i) absent.
// ---------------------------------------------------------------------------
__global__ __launch_bounds__(256) void final_kernel(const float* __restrict__ x6,
                             const int* __restrict__ roffsets, const int* __restrict__ rcsr,
                             const float* __restrict__ x1, const float* __restrict__ lw,
                             float* __restrict__ out, int n) {
    int wave = threadIdx.x >> 6;
    int lane = threadIdx.x & 63;
    int node = blockIdx.x * 4 + wave;
    if (node >= n) return;
    int beg = roffsets[node], end = roffsets[node + 1];
    int d = end - beg;
    const float4* x6v = (const float4*)x6;
    float4 s0 = make_float4(0.f, 0.f, 0.f, 0.f);
    float4 s1 = make_float4(0.f, 0.f, 0.f, 0.f);
    int ndl = 0;
    bool selfl = false;
    if (d <= 64) {
        int c = (lane < d) ? rcsr[beg + lane] : -1;
        bool dup = false;
        for (int t = 0; t < d - 1; t++) {
            int v = __shfl(c, t, 64);          // uniform t -> v_readlane
            dup |= (lane > t) && (c == v);
        }
        if ((lane < d) && !dup) {
            ndl = 1;
            selfl = (c == node);
            s0 = x6v[(size_t)c * 2];
            s1 = x6v[(size_t)c * 2 + 1];
        }
    } else {
        for (int k = beg + lane; k < end; k += 64) {
            int c = rcsr[k];
            bool dup = false;
            for (int j = beg; j < k; j++) if (rcsr[j] == c) { dup = true; break; }
            if (!dup) {
                ndl++;
                selfl |= (c == node);
                float4 a = x6v[(size_t)c * 2];
                float4 b = x6v[(size_t)c * 2 + 1];
                s0.x += a.x; s0.y += a.y; s0.z += a.z; s0.w += a.w;
                s1.x += b.x; s1.y += b.y; s1.z += b.z; s1.w += b.w;
            }
        }
    }
    // butterfly reduction across the 64-lane wave
    for (int off = 32; off > 0; off >>= 1) {
        s0.x += __shfl_xor(s0.x, off, 64);
        s0.y += __shfl_xor(s0.y, off, 64);
        s0.z += __shfl_xor(s0.z, off, 64);
        s0.w += __shfl_xor(s0.w, off, 64);
        s1.x += __shfl_xor(s1.x, off, 64);
        s1.y += __shfl_xor(s1.y, off, 64);
        s1.z += __shfl_xor(s1.z, off, 64);
        s1.w += __shfl_xor(s1.w, off, 64);
        ndl  += __shfl_xor(ndl, off, 64);
    }
    bool selfSet = __any(selfl);
    if (lane == 0) {
        float4 me0 = x6v[(size_t)node * 2];
        float4 me1 = x6v[(size_t)node * 2 + 1];
        if (!selfSet) {
            s0.x += me0.x; s0.y += me0.y; s0.z += me0.z; s0.w += me0.w;
            s1.x += me1.x; s1.y += me1.y; s1.z += me1.z; s1.w += me1.w;
            ndl += 1;
        }
        float r2 = s0.x * me0.x + s0.y * me0.y + s0.z * me0.z + s0.w * me0.w
                 + s1.x * me1.x + s1.y * me1.y + s1.z * me1.z + s1.w * me1.w;
        float gs = s0.x * lw[0] + s0.y * lw[1] + s0.z * lw[2] + s0.w * lw[3]
                 + s1.x * lw[4] + s1.y * lw[5] + s1.z * lw[6] + s1.w * lw[7];
        out[node] = (r2 + gs) / (float)ndl + x1[(size_t)node * 10];
    }
}

static inline size_t align16(size_t x) { return (x + 15) & ~(size_t)15; }

extern "C" void kernel_launch(void* const* d_in, const int* in_sizes, int n_in,
                              void* d_out, int out_size, void* d_ws, size_t ws_size,
                              hipStream_t stream) {
    const float* x1  = (const float*)d_in[0];
    // x2 (d_in[1]) is unused by the reference
    const int*   edge = (const int*)d_in[2];
    const float* W1  = (const float*)d_in[4];
    const float* as1 = (const float*)d_in[5];
    const float* ad1 = (const float*)d_in[6];
    const float* b1  = (const float*)d_in[7];
    const float* W2  = (const float*)d_in[8];
    const float* as2 = (const float*)d_in[9];
    const float* ad2 = (const float*)d_in[10];
    const float* b2  = (const float*)d_in[11];
    const float* W3  = (const float*)d_in[12];
    const float* as3 = (const float*)d_in[13];
    const float* ad3 = (const float*)d_in[14];
    const float* b3  = (const float*)d_in[15];
    const float* lw  = (const float*)d_in[16];
    float* out = (float*)d_out;

    const int n = in_sizes[0] / 10;     // 10000
    const int E = in_sizes[2] / 2;      // 320000

    // ---- workspace layout (16B aligned blocks) ----
    char* p = (char*)d_ws;
    int*   cnt     = (int*)p;   p += align16((size_t)n * 4);
    int*   rcnt    = (int*)p;   p += align16((size_t)n * 4);
    size_t zbytes  = (size_t)(p - (char*)d_ws);      // zero-init region ends here
    int*   fill    = (int*)p;   p += align16((size_t)n * 4);
    int*   rfill   = (int*)p;   p += align16((size_t)n * 4);
    int*   offsets = (int*)p;   p += align16((size_t)(n + 1) * 4);
    int*   roffsets= (int*)p;   p += align16((size_t)(n + 1) * 4);
    int*   csr     = (int*)p;   p += align16((size_t)(E + n) * 4);
    int*   rcsr    = (int*)p;   p += align16((size_t)E * 4);
    float* h1  = (float*)p; p += align16((size_t)n * 32 * 4);
    float* es1 = (float*)p; p += align16((size_t)n * 8 * 4);
    float* ed1 = (float*)p; p += align16((size_t)n * 8 * 4);
    float* x3  = (float*)p; p += align16((size_t)n * 32 * 4);
    float* h2  = (float*)p; p += align16((size_t)n * 16 * 4);
    float* es2 = (float*)p; p += align16((size_t)n * 4 * 4);
    float* ed2 = (float*)p; p += align16((size_t)n * 4 * 4);
    float* x4  = (float*)p; p += align16((size_t)n * 16 * 4);
    float* h3  = (float*)p; p += align16((size_t)n * 8 * 4);
    float* es3 = (float*)p; p += align16((size_t)n * 2 * 4);
    float* ed3 = (float*)p; p += align16((size_t)n * 2 * 4);
    float* x6  = (float*)p; p += align16((size_t)n * 8 * 4);

    hipMemsetAsync(d_ws, 0, zbytes, stream);   // just cnt + rcnt (80 KB)

    int e4bl = (E + TPB * 4 - 1) / (TPB * 4);
    int nbl  = (n + TPB - 1) / TPB;

    count_kernel<<<e4bl, TPB, 0, stream>>>(edge, E, cnt, rcnt);
    scan_kernel<<<1, 1024, 0, stream>>>(cnt, rcnt, offsets, fill, csr, roffsets, rfill, n);
    scatter_kernel<<<e4bl, TPB, 0, stream>>>(edge, E, fill, csr, rfill, rcsr);

    // layer 1: IN=10, H=8
    transform_kernel<10, 8><<<nbl, TPB, 0, stream>>>(x1, W1, as1, ad1, n, h1, es1, ed1);
    aggregate_kernel<8><<<(n * 8 + TPB - 1) / TPB, TPB, 0, stream>>>(
        offsets, csr, h1, es1, ed1, b1, n, x3);

    // layer 2: IN=32, H=4
    transform_kernel<32, 4><<<nbl, TPB, 0, stream>>>(x3, W2, as2, ad2, n, h2, es2, ed2);
    aggregate_kernel<4><<<(n * 4 + TPB - 1) / TPB, TPB, 0, stream>>>(
        offsets, csr, h2, es2, ed2, b2, n, x4);

    // layer 3: IN=16, H=2
    transform_kernel<16, 2><<<nbl, TPB, 0, stream>>>(x4, W3, as3, ad3, n, h3, es3, ed3);
    aggregate_kernel<2><<<(n * 2 + TPB - 1) / TPB, TPB, 0, stream>>>(
        offsets, csr, h3, es3, ed3, b3, n, x6);

    // fused scoring epilogue: one wave per node, shuffle-based dedup
    final_kernel<<<(n + 3) / 4, 256, 0, stream>>>(x6, roffsets, rcsr, x1, lw, out, n);
}

// Round 6
// 278.874 us; speedup vs baseline: 1.6296x; 1.0628x over previous
//
#include <hip/hip_runtime.h>

#define TPB 256

// ---------------------------------------------------------------------------
// Per-edge histogram: cnt[c] = in-degree (dup kept), rcnt[r] = out-degree
// (dup kept). 4 edges/thread for independent atomic chains.
// ---------------------------------------------------------------------------
__global__ void count_kernel(const int* __restrict__ edge, int E,
                             int* __restrict__ cnt, int* __restrict__ rcnt) {
    int base = (blockIdx.x * blockDim.x + threadIdx.x) * 4;
    int r[4], c[4];
    int m = E - base; if (m <= 0) return; if (m > 4) m = 4;
    for (int u = 0; u < m; u++) { r[u] = edge[base + u]; c[u] = edge[E + base + u]; }
    for (int u = 0; u < m; u++) {
        atomicAdd(&rcnt[r[u]], 1);
        atomicAdd(&cnt[c[u]], 1);
    }
}

// ---------------------------------------------------------------------------
// Single-block hierarchical pair-scan, 2 barriers total:
//   thread t serially sums its ceil(n/1024)-chunk of (cnt[i]+1, rcnt[i])
//   -> wave shfl_up inclusive scan of per-thread sums (no barrier)
//   -> wave 0 scans the 16 wave totals
//   -> threads write back chunk prefixes:
//      offsets (dst-CSR, self-loop at segment head), fill, csr[excl]=i,
//      roffsets (row-CSR), rfill.
// ---------------------------------------------------------------------------
__global__ __launch_bounds__(1024) void scan_kernel(
        const int* __restrict__ cnt, const int* __restrict__ rcnt,
        int* __restrict__ offsets, int* __restrict__ fill,
        int* __restrict__ csr,
        int* __restrict__ roffsets, int* __restrict__ rfill,
        int n) {
    const int T = 1024;
    int t = threadIdx.x;
    int wave = t >> 6, lane = t & 63;
    int CH = (n + T - 1) / T;
    int ibeg = t * CH;
    int iend = ibeg + CH; if (iend > n) iend = n;

    int suma = 0, sumb = 0;
    for (int i = ibeg; i < iend; i++) { suma += cnt[i] + 1; sumb += rcnt[i]; }

    // wave-level inclusive scan of per-thread sums (pairwise)
    int ia = suma, ib = sumb;
    for (int off = 1; off < 64; off <<= 1) {
        int ta = __shfl_up(ia, off, 64);
        int tb = __shfl_up(ib, off, 64);
        if (lane >= off) { ia += ta; ib += tb; }
    }

    __shared__ int wsA[16], wsB[16], wpA[16], wpB[16], gtot[2];
    if (lane == 63) { wsA[wave] = ia; wsB[wave] = ib; }
    __syncthreads();
    if (wave == 0 && lane < 16) {
        int a = wsA[lane], b = wsB[lane];
        int pa = a, pb = b;
        for (int off = 1; off < 16; off <<= 1) {
            int ta = __shfl_up(pa, off, 64);
            int tb = __shfl_up(pb, off, 64);
            if (lane >= off) { pa += ta; pb += tb; }
        }
        wpA[lane] = pa - a;   // exclusive wave prefix
        wpB[lane] = pb - b;
        if (lane == 15) { gtot[0] = pa; gtot[1] = pb; }
    }
    __syncthreads();

    int exA = wpA[wave] + ia - suma;   // this thread's global exclusive prefix
    int exB = wpB[wave] + ib - sumb;
    for (int i = ibeg; i < iend; i++) {
        int va = cnt[i] + 1;
        offsets[i] = exA;
        fill[i]    = exA + 1;   // slot 0 of the segment = self loop
        csr[exA]   = i;         // self-loop src
        exA += va;
        roffsets[i] = exB;
        rfill[i]    = exB;
        exB += rcnt[i];
    }
    if (t == 0) { offsets[n] = gtot[0]; roffsets[n] = gtot[1]; }   // E+n, E
}

// ---------------------------------------------------------------------------
// Scatter into dst-CSR (srcs grouped by dst) and row-CSR (dsts grouped by
// src, duplicates kept). 4 edges/thread.
// ---------------------------------------------------------------------------
__global__ void scatter_kernel(const int* __restrict__ edge, int E,
                               int* __restrict__ fill, int* __restrict__ csr,
                               int* __restrict__ rfill, int* __restrict__ rcsr) {
    int base = (blockIdx.x * blockDim.x + threadIdx.x) * 4;
    int r[4], c[4];
    int m = E - base; if (m <= 0) return; if (m > 4) m = 4;
    for (int u = 0; u < m; u++) { r[u] = edge[base + u]; c[u] = edge[E + base + u]; }
    for (int u = 0; u < m; u++) {
        int p = atomicAdd(&fill[c[u]], 1);
        csr[p] = r[u];
        int q = atomicAdd(&rfill[r[u]], 1);
        rcsr[q] = c[u];
    }
}

// ---------------------------------------------------------------------------
// h = x @ W (per node) + per-head attention logits. Templated so xv[] stays
// in registers and loops fully unroll. W, a_src, a_dst staged in LDS.
// ---------------------------------------------------------------------------
template <int IN, int H>
__global__ void transform_kernel(const float* __restrict__ x, const float* __restrict__ W,
                                 const float* __restrict__ asrc, const float* __restrict__ adst,
                                 int n, float* __restrict__ h, float* __restrict__ es,
                                 float* __restrict__ ed) {
    constexpr int HC = H * 4;
    __shared__ float sW[IN * HC];
    __shared__ float sa[HC];
    __shared__ float sd[HC];
    for (int i = threadIdx.x; i < IN * HC; i += blockDim.x) sW[i] = W[i];
    if (threadIdx.x < HC) { sa[threadIdx.x] = asrc[threadIdx.x]; sd[threadIdx.x] = adst[threadIdx.x]; }
    __syncthreads();
    int node = blockIdx.x * blockDim.x + threadIdx.x;
    if (node >= n) return;
    float xv[IN];
#pragma unroll
    for (int k = 0; k < IN; k++) xv[k] = x[(size_t)node * IN + k];
#pragma unroll
    for (int hd = 0; hd < H; hd++) {
        float e1 = 0.f, e2 = 0.f;
#pragma unroll
        for (int c = 0; c < 4; c++) {
            int o = hd * 4 + c;
            float acc = 0.f;
#pragma unroll
            for (int k = 0; k < IN; k++) acc += xv[k] * sW[k * HC + o];
            h[(size_t)node * HC + o] = acc;
            e1 += acc * sa[o];
            e2 += acc * sd[o];
        }
        es[(size_t)node * H + hd] = e1;
        ed[(size_t)node * H + hd] = e2;
    }
}

// ---------------------------------------------------------------------------
// Segment softmax + aggregation, one thread per (dst, head), ONE pass using
// online softmax (running max + rescale). Epilogue: /denom, +bias, relu.
// ---------------------------------------------------------------------------
template <int H>
__global__ void aggregate_kernel(const int* __restrict__ offsets, const int* __restrict__ csr,
                                 const float* __restrict__ h, const float* __restrict__ es,
                                 const float* __restrict__ ed, const float* __restrict__ bias,
                                 int n, float* __restrict__ xout) {
    constexpr int HC = H * 4;
    int tid = blockIdx.x * blockDim.x + threadIdx.x;
    if (tid >= n * H) return;
    int node = tid / H;
    int hd   = tid % H;
    int beg = offsets[node], end = offsets[node + 1];
    float edv = ed[(size_t)node * H + hd];
    float m = -1e30f, denom = 0.f;
    float4 acc = make_float4(0.f, 0.f, 0.f, 0.f);
    for (int k = beg; k < end; k++) {
        int s = csr[k];
        float e = es[(size_t)s * H + hd] + edv;
        e = (e > 0.f) ? e : 0.2f * e;
        if (e > m) {
            float sc = __expf(m - e);      // first iter: expf(-huge) = 0
            denom *= sc;
            acc.x *= sc; acc.y *= sc; acc.z *= sc; acc.w *= sc;
            m = e;
        }
        float w = __expf(e - m);
        float4 hv = *(const float4*)&h[(size_t)s * HC + hd * 4];
        denom += w;
        acc.x += w * hv.x;
        acc.y += w * hv.y;
        acc.z += w * hv.z;
        acc.w += w * hv.w;
    }
    float inv = 1.0f / denom;
    float* op = &xout[(size_t)node * HC + hd * 4];
    const float* bp = &bias[hd * 4];
    float v;
    v = acc.x * inv + bp[0]; op[0] = v > 0.f ? v : 0.f;
    v = acc.y * inv + bp[1]; op[1] = v > 0.f ? v : 0.f;
    v = acc.z * inv + bp[2]; op[2] = v > 0.f ? v : 0.f;
    v = acc.w * inv + bp[3]; op[3] = v > 0.f ? v : 0.f;
}

// ---------------------------------------------------------------------------
// Fused scoring epilogue, ONE WAVE PER NODE (wave-parallel dedup).
// Row segment (duplicates kept): lane l holds element l; first-occurrence
// test via uniform __shfl broadcasts (d<=64 fast path). Winner lanes gather
// x6[c] (L2-resident), butterfly-reduce. d>64: per-lane global scan fallback.
//   out[i] = (x6[i]·s_i + s_i·lin2_w)/deg_i + x1[i,0]
// Diagonal contributes iff edge (i,i) absent.
// ---------------------------------------------------------------------------
__global__ __launch_bounds__(256) void final_kernel(const float* __restrict__ x6,
                             const int* __restrict__ roffsets, const int* __restrict__ rcsr,
                             const float* __restrict__ x1, const float* __restrict__ lw,
                             float* __restrict__ out, int n) {
    int wave = threadIdx.x >> 6;
    int lane = threadIdx.x & 63;
    int node = blockIdx.x * 4 + wave;
    if (node >= n) return;
    int beg = roffsets[node], end = roffsets[node + 1];
    int d = end - beg;
    const float4* x6v = (const float4*)x6;
    float4 s0 = make_float4(0.f, 0.f, 0.f, 0.f);
    float4 s1 = make_float4(0.f, 0.f, 0.f, 0.f);
    int ndl = 0;
    bool selfl = false;
    if (d <= 64) {
        int c = (lane < d) ? rcsr[beg + lane] : -1;
        bool dup = false;
        for (int t = 0; t < d - 1; t++) {
            int v = __shfl(c, t, 64);          // uniform t -> v_readlane
            dup |= (lane > t) && (c == v);
        }
        if ((lane < d) && !dup) {
            ndl = 1;
            selfl = (c == node);
            s0 = x6v[(size_t)c * 2];
            s1 = x6v[(size_t)c * 2 + 1];
        }
    } else {
        for (int k = beg + lane; k < end; k += 64) {
            int c = rcsr[k];
            bool dup = false;
            for (int j = beg; j < k; j++) if (rcsr[j] == c) { dup = true; break; }
            if (!dup) {
                ndl++;
                selfl |= (c == node);
                float4 a = x6v[(size_t)c * 2];
                float4 b = x6v[(size_t)c * 2 + 1];
                s0.x += a.x; s0.y += a.y; s0.z += a.z; s0.w += a.w;
                s1.x += b.x; s1.y += b.y; s1.z += b.z; s1.w += b.w;
            }
        }
    }
    // butterfly reduction across the 64-lane wave
    for (int off = 32; off > 0; off >>= 1) {
        s0.x += __shfl_xor(s0.x, off, 64);
        s0.y += __shfl_xor(s0.y, off, 64);
        s0.z += __shfl_xor(s0.z, off, 64);
        s0.w += __shfl_xor(s0.w, off, 64);
        s1.x += __shfl_xor(s1.x, off, 64);
        s1.y += __shfl_xor(s1.y, off, 64);
        s1.z += __shfl_xor(s1.z, off, 64);
        s1.w += __shfl_xor(s1.w, off, 64);
        ndl  += __shfl_xor(ndl, off, 64);
    }
    bool selfSet = __any(selfl);
    if (lane == 0) {
        float4 me0 = x6v[(size_t)node * 2];
        float4 me1 = x6v[(size_t)node * 2 + 1];
        if (!selfSet) {
            s0.x += me0.x; s0.y += me0.y; s0.z += me0.z; s0.w += me0.w;
            s1.x += me1.x; s1.y += me1.y; s1.z += me1.z; s1.w += me1.w;
            ndl += 1;
        }
        float r2 = s0.x * me0.x + s0.y * me0.y + s0.z * me0.z + s0.w * me0.w
                 + s1.x * me1.x + s1.y * me1.y + s1.z * me1.z + s1.w * me1.w;
        float gs = s0.x * lw[0] + s0.y * lw[1] + s0.z * lw[2] + s0.w * lw[3]
                 + s1.x * lw[4] + s1.y * lw[5] + s1.z * lw[6] + s1.w * lw[7];
        out[node] = (r2 + gs) / (float)ndl + x1[(size_t)node * 10];
    }
}

static inline size_t align16(size_t x) { return (x + 15) & ~(size_t)15; }

extern "C" void kernel_launch(void* const* d_in, const int* in_sizes, int n_in,
                              void* d_out, int out_size, void* d_ws, size_t ws_size,
                              hipStream_t stream) {
    const float* x1  = (const float*)d_in[0];
    // x2 (d_in[1]) is unused by the reference
    const int*   edge = (const int*)d_in[2];
    const float* W1  = (const float*)d_in[4];
    const float* as1 = (const float*)d_in[5];
    const float* ad1 = (const float*)d_in[6];
    const float* b1  = (const float*)d_in[7];
    const float* W2  = (const float*)d_in[8];
    const float* as2 = (const float*)d_in[9];
    const float* ad2 = (const float*)d_in[10];
    const float* b2  = (const float*)d_in[11];
    const float* W3  = (const float*)d_in[12];
    const float* as3 = (const float*)d_in[13];
    const float* ad3 = (const float*)d_in[14];
    const float* b3  = (const float*)d_in[15];
    const float* lw  = (const float*)d_in[16];
    float* out = (float*)d_out;

    const int n = in_sizes[0] / 10;     // 10000
    const int E = in_sizes[2] / 2;      // 320000

    // ---- workspace layout (16B aligned blocks) ----
    char* p = (char*)d_ws;
    int*   cnt     = (int*)p;   p += align16((size_t)n * 4);
    int*   rcnt    = (int*)p;   p += align16((size_t)n * 4);
    size_t zbytes  = (size_t)(p - (char*)d_ws);      // zero-init region ends here
    int*   fill    = (int*)p;   p += align16((size_t)n * 4);
    int*   rfill   = (int*)p;   p += align16((size_t)n * 4);
    int*   offsets = (int*)p;   p += align16((size_t)(n + 1) * 4);
    int*   roffsets= (int*)p;   p += align16((size_t)(n + 1) * 4);
    int*   csr     = (int*)p;   p += align16((size_t)(E + n) * 4);
    int*   rcsr    = (int*)p;   p += align16((size_t)E * 4);
    float* h1  = (float*)p; p += align16((size_t)n * 32 * 4);
    float* es1 = (float*)p; p += align16((size_t)n * 8 * 4);
    float* ed1 = (float*)p; p += align16((size_t)n * 8 * 4);
    float* x3  = (float*)p; p += align16((size_t)n * 32 * 4);
    float* h2  = (float*)p; p += align16((size_t)n * 16 * 4);
    float* es2 = (float*)p; p += align16((size_t)n * 4 * 4);
    float* ed2 = (float*)p; p += align16((size_t)n * 4 * 4);
    float* x4  = (float*)p; p += align16((size_t)n * 16 * 4);
    float* h3  = (float*)p; p += align16((size_t)n * 8 * 4);
    float* es3 = (float*)p; p += align16((size_t)n * 2 * 4);
    float* ed3 = (float*)p; p += align16((size_t)n * 2 * 4);
    float* x6  = (float*)p; p += align16((size_t)n * 8 * 4);

    hipMemsetAsync(d_ws, 0, zbytes, stream);   // just cnt + rcnt (80 KB)

    int e4bl = (E + TPB * 4 - 1) / (TPB * 4);
    int nbl  = (n + TPB - 1) / TPB;

    count_kernel<<<e4bl, TPB, 0, stream>>>(edge, E, cnt, rcnt);
    scan_kernel<<<1, 1024, 0, stream>>>(cnt, rcnt, offsets, fill, csr, roffsets, rfill, n);
    scatter_kernel<<<e4bl, TPB, 0, stream>>>(edge, E, fill, csr, rfill, rcsr);

    // layer 1: IN=10, H=8
    transform_kernel<10, 8><<<nbl, TPB, 0, stream>>>(x1, W1, as1, ad1, n, h1, es1, ed1);
    aggregate_kernel<8><<<(n * 8 + TPB - 1) / TPB, TPB, 0, stream>>>(
        offsets, csr, h1, es1, ed1, b1, n, x3);

    // layer 2: IN=32, H=4
    transform_kernel<32, 4><<<nbl, TPB, 0, stream>>>(x3, W2, as2, ad2, n, h2, es2, ed2);
    aggregate_kernel<4><<<(n * 4 + TPB - 1) / TPB, TPB, 0, stream>>>(
        offsets, csr, h2, es2, ed2, b2, n, x4);

    // layer 3: IN=16, H=2
    transform_kernel<16, 2><<<nbl, TPB, 0, stream>>>(x4, W3, as3, ad3, n, h3, es3, ed3);
    aggregate_kernel<2><<<(n * 2 + TPB - 1) / TPB, TPB, 0, stream>>>(
        offsets, csr, h3, es3, ed3, b3, n, x6);

    // fused scoring epilogue: one wave per node, shuffle-based dedup
    final_kernel<<<(n + 3) / 4, 256, 0, stream>>>(x6, roffsets, rcsr, x1, lw, out, n);
}

// Round 7
// 275.411 us; speedup vs baseline: 1.6501x; 1.0126x over previous
//
#include <hip/hip_runtime.h>

#define TPB 256

// ---------------------------------------------------------------------------
// Per-edge histogram: cnt[c] = in-degree (dup kept), rcnt[r] = out-degree
// (dup kept). 1 edge/thread: max wave count for atomic latency hiding.
// ---------------------------------------------------------------------------
__global__ void count_kernel(const int* __restrict__ edge, int E,
                             int* __restrict__ cnt, int* __restrict__ rcnt) {
    int e = blockIdx.x * blockDim.x + threadIdx.x;
    if (e >= E) return;
    atomicAdd(&rcnt[edge[e]], 1);
    atomicAdd(&cnt[edge[E + e]], 1);
}

// ---------------------------------------------------------------------------
// Single-block hierarchical pair-scan, 2 barriers total:
//   thread t serially sums its ceil(n/1024)-chunk of (cnt[i]+1, rcnt[i])
//   -> wave shfl_up inclusive scan of per-thread sums (no barrier)
//   -> wave 0 scans the 16 wave totals
//   -> threads write back chunk prefixes:
//      offsets (dst-CSR, self-loop at segment head), fill, csr[excl]=i,
//      roffsets (row-CSR), rfill.
// ---------------------------------------------------------------------------
__global__ __launch_bounds__(1024) void scan_kernel(
        const int* __restrict__ cnt, const int* __restrict__ rcnt,
        int* __restrict__ offsets, int* __restrict__ fill,
        int* __restrict__ csr,
        int* __restrict__ roffsets, int* __restrict__ rfill,
        int n) {
    const int T = 1024;
    int t = threadIdx.x;
    int wave = t >> 6, lane = t & 63;
    int CH = (n + T - 1) / T;
    int ibeg = t * CH;
    int iend = ibeg + CH; if (iend > n) iend = n;

    int suma = 0, sumb = 0;
    for (int i = ibeg; i < iend; i++) { suma += cnt[i] + 1; sumb += rcnt[i]; }

    // wave-level inclusive scan of per-thread sums (pairwise)
    int ia = suma, ib = sumb;
    for (int off = 1; off < 64; off <<= 1) {
        int ta = __shfl_up(ia, off, 64);
        int tb = __shfl_up(ib, off, 64);
        if (lane >= off) { ia += ta; ib += tb; }
    }

    __shared__ int wsA[16], wsB[16], wpA[16], wpB[16], gtot[2];
    if (lane == 63) { wsA[wave] = ia; wsB[wave] = ib; }
    __syncthreads();
    if (wave == 0 && lane < 16) {
        int a = wsA[lane], b = wsB[lane];
        int pa = a, pb = b;
        for (int off = 1; off < 16; off <<= 1) {
            int ta = __shfl_up(pa, off, 64);
            int tb = __shfl_up(pb, off, 64);
            if (lane >= off) { pa += ta; pb += tb; }
        }
        wpA[lane] = pa - a;   // exclusive wave prefix
        wpB[lane] = pb - b;
        if (lane == 15) { gtot[0] = pa; gtot[1] = pb; }
    }
    __syncthreads();

    int exA = wpA[wave] + ia - suma;   // this thread's global exclusive prefix
    int exB = wpB[wave] + ib - sumb;
    for (int i = ibeg; i < iend; i++) {
        int va = cnt[i] + 1;
        offsets[i] = exA;
        fill[i]    = exA + 1;   // slot 0 of the segment = self loop
        csr[exA]   = i;         // self-loop src
        exA += va;
        roffsets[i] = exB;
        rfill[i]    = exB;
        exB += rcnt[i];
    }
    if (t == 0) { offsets[n] = gtot[0]; roffsets[n] = gtot[1]; }   // E+n, E
}

// ---------------------------------------------------------------------------
// Scatter into dst-CSR (srcs grouped by dst) and row-CSR (dsts grouped by
// src, duplicates kept). 1 edge/thread.
// ---------------------------------------------------------------------------
__global__ void scatter_kernel(const int* __restrict__ edge, int E,
                               int* __restrict__ fill, int* __restrict__ csr,
                               int* __restrict__ rfill, int* __restrict__ rcsr) {
    int e = blockIdx.x * blockDim.x + threadIdx.x;
    if (e >= E) return;
    int r = edge[e];
    int c = edge[E + e];
    int p = atomicAdd(&fill[c], 1);
    csr[p] = r;
    int q = atomicAdd(&rfill[r], 1);
    rcsr[q] = c;
}

// ---------------------------------------------------------------------------
// h = x @ W + attention logits, one thread per (node, head): H x more
// parallelism than per-node. W, a_src, a_dst staged in LDS.
// ---------------------------------------------------------------------------
template <int IN, int H>
__global__ void transform_kernel(const float* __restrict__ x, const float* __restrict__ W,
                                 const float* __restrict__ asrc, const float* __restrict__ adst,
                                 int n, float* __restrict__ h, float* __restrict__ es,
                                 float* __restrict__ ed) {
    constexpr int HC = H * 4;
    __shared__ float sW[IN * HC];
    __shared__ float sa[HC];
    __shared__ float sd[HC];
    for (int i = threadIdx.x; i < IN * HC; i += blockDim.x) sW[i] = W[i];
    if (threadIdx.x < HC) { sa[threadIdx.x] = asrc[threadIdx.x]; sd[threadIdx.x] = adst[threadIdx.x]; }
    __syncthreads();
    int tid = blockIdx.x * blockDim.x + threadIdx.x;
    if (tid >= n * H) return;
    int node = tid / H;
    int hd   = tid % H;
    float xv[IN];
#pragma unroll
    for (int k = 0; k < IN; k++) xv[k] = x[(size_t)node * IN + k];
    float e1 = 0.f, e2 = 0.f;
    float4 hv;
    float* hp = &hv.x;
#pragma unroll
    for (int c = 0; c < 4; c++) {
        int o = hd * 4 + c;
        float acc = 0.f;
#pragma unroll
        for (int k = 0; k < IN; k++) acc += xv[k] * sW[k * HC + o];
        hp[c] = acc;
        e1 += acc * sa[o];
        e2 += acc * sd[o];
    }
    *(float4*)&h[(size_t)node * HC + hd * 4] = hv;
    es[(size_t)node * H + hd] = e1;
    ed[(size_t)node * H + hd] = e2;
}

// ---------------------------------------------------------------------------
// Segment softmax + aggregation, ONE WAVE per (dst, head). Lanes stride the
// incoming-edge segment (coalesced csr reads, 64 random es/h gathers in
// flight), lane-local online softmax, butterfly merge (max + rescale).
// Epilogue: /denom, +bias, relu; lane 0 stores float4.
// ---------------------------------------------------------------------------
template <int H>
__global__ __launch_bounds__(256) void aggregate_kernel(
        const int* __restrict__ offsets, const int* __restrict__ csr,
        const float* __restrict__ h, const float* __restrict__ es,
        const float* __restrict__ ed, const float* __restrict__ bias,
        int n, float* __restrict__ xout) {
    constexpr int HC = H * 4;
    int gw = blockIdx.x * 4 + (threadIdx.x >> 6);
    int lane = threadIdx.x & 63;
    if (gw >= n * H) return;
    int node = gw / H;
    int hd   = gw % H;
    int beg = offsets[node], end = offsets[node + 1];
    float edv = ed[(size_t)node * H + hd];
    float m = -1e30f, den = 0.f;
    float4 acc = make_float4(0.f, 0.f, 0.f, 0.f);
    for (int k = beg + lane; k < end; k += 64) {
        int s = csr[k];
        float e = es[(size_t)s * H + hd] + edv;
        e = (e > 0.f) ? e : 0.2f * e;
        if (e > m) {
            float sc = __expf(m - e);      // first iter: expf(-huge) = 0
            den *= sc;
            acc.x *= sc; acc.y *= sc; acc.z *= sc; acc.w *= sc;
            m = e;
        }
        float w = __expf(e - m);
        float4 hv = *(const float4*)&h[(size_t)s * HC + hd * 4];
        den += w;
        acc.x += w * hv.x;
        acc.y += w * hv.y;
        acc.z += w * hv.z;
        acc.w += w * hv.w;
    }
    // butterfly merge of (m, den, acc) across the wave
    for (int off = 32; off > 0; off >>= 1) {
        float m2 = __shfl_xor(m, off, 64);
        float d2 = __shfl_xor(den, off, 64);
        float ax = __shfl_xor(acc.x, off, 64);
        float ay = __shfl_xor(acc.y, off, 64);
        float az = __shfl_xor(acc.z, off, 64);
        float aw = __shfl_xor(acc.w, off, 64);
        float M = fmaxf(m, m2);
        float sA = __expf(m - M);
        float sB = __expf(m2 - M);
        den  = den * sA + d2 * sB;
        acc.x = acc.x * sA + ax * sB;
        acc.y = acc.y * sA + ay * sB;
        acc.z = acc.z * sA + az * sB;
        acc.w = acc.w * sA + aw * sB;
        m = M;
    }
    if (lane == 0) {
        float inv = 1.0f / den;
        const float* bp = &bias[hd * 4];
        float4 o;
        float v;
        v = acc.x * inv + bp[0]; o.x = v > 0.f ? v : 0.f;
        v = acc.y * inv + bp[1]; o.y = v > 0.f ? v : 0.f;
        v = acc.z * inv + bp[2]; o.z = v > 0.f ? v : 0.f;
        v = acc.w * inv + bp[3]; o.w = v > 0.f ? v : 0.f;
        *(float4*)&xout[(size_t)node * HC + hd * 4] = o;
    }
}

// ---------------------------------------------------------------------------
// Fused scoring epilogue, ONE WAVE PER NODE (wave-parallel dedup).
// Row segment (duplicates kept): lane l holds element l; first-occurrence
// test via uniform __shfl broadcasts (d<=64 fast path). Winner lanes gather
// x6[c] (L2-resident), butterfly-reduce. d>64: per-lane global scan fallback.
//   out[i] = (x6[i]·s_i + s_i·lin2_w)/deg_i + x1[i,0]
// Diagonal contributes iff edge (i,i) absent.
// ---------------------------------------------------------------------------
__global__ __launch_bounds__(256) void final_kernel(const float* __restrict__ x6,
                             const int* __restrict__ roffsets, const int* __restrict__ rcsr,
                             const float* __restrict__ x1, const float* __restrict__ lw,
                             float* __restrict__ out, int n) {
    int wave = threadIdx.x >> 6;
    int lane = threadIdx.x & 63;
    int node = blockIdx.x * 4 + wave;
    if (node >= n) return;
    int beg = roffsets[node], end = roffsets[node + 1];
    int d = end - beg;
    const float4* x6v = (const float4*)x6;
    float4 s0 = make_float4(0.f, 0.f, 0.f, 0.f);
    float4 s1 = make_float4(0.f, 0.f, 0.f, 0.f);
    int ndl = 0;
    bool selfl = false;
    if (d <= 64) {
        int c = (lane < d) ? rcsr[beg + lane] : -1;
        bool dup = false;
        for (int t = 0; t < d - 1; t++) {
            int v = __shfl(c, t, 64);          // uniform t -> v_readlane
            dup |= (lane > t) && (c == v);
        }
        if ((lane < d) && !dup) {
            ndl = 1;
            selfl = (c == node);
            s0 = x6v[(size_t)c * 2];
            s1 = x6v[(size_t)c * 2 + 1];
        }
    } else {
        for (int k = beg + lane; k < end; k += 64) {
            int c = rcsr[k];
            bool dup = false;
            for (int j = beg; j < k; j++) if (rcsr[j] == c) { dup = true; break; }
            if (!dup) {
                ndl++;
                selfl |= (c == node);
                float4 a = x6v[(size_t)c * 2];
                float4 b = x6v[(size_t)c * 2 + 1];
                s0.x += a.x; s0.y += a.y; s0.z += a.z; s0.w += a.w;
                s1.x += b.x; s1.y += b.y; s1.z += b.z; s1.w += b.w;
            }
        }
    }
    // butterfly reduction across the 64-lane wave
    for (int off = 32; off > 0; off >>= 1) {
        s0.x += __shfl_xor(s0.x, off, 64);
        s0.y += __shfl_xor(s0.y, off, 64);
        s0.z += __shfl_xor(s0.z, off, 64);
        s0.w += __shfl_xor(s0.w, off, 64);
        s1.x += __shfl_xor(s1.x, off, 64);
        s1.y += __shfl_xor(s1.y, off, 64);
        s1.z += __shfl_xor(s1.z, off, 64);
        s1.w += __shfl_xor(s1.w, off, 64);
        ndl  += __shfl_xor(ndl, off, 64);
    }
    bool selfSet = __any(selfl);
    if (lane == 0) {
        float4 me0 = x6v[(size_t)node * 2];
        float4 me1 = x6v[(size_t)node * 2 + 1];
        if (!selfSet) {
            s0.x += me0.x; s0.y += me0.y; s0.z += me0.z; s0.w += me0.w;
            s1.x += me1.x; s1.y += me1.y; s1.z += me1.z; s1.w += me1.w;
            ndl += 1;
        }
        float r2 = s0.x * me0.x + s0.y * me0.y + s0.z * me0.z + s0.w * me0.w
                 + s1.x * me1.x + s1.y * me1.y + s1.z * me1.z + s1.w * me1.w;
        float gs = s0.x * lw[0] + s0.y * lw[1] + s0.z * lw[2] + s0.w * lw[3]
                 + s1.x * lw[4] + s1.y * lw[5] + s1.z * lw[6] + s1.w * lw[7];
        out[node] = (r2 + gs) / (float)ndl + x1[(size_t)node * 10];
    }
}

static inline size_t align16(size_t x) { return (x + 15) & ~(size_t)15; }

extern "C" void kernel_launch(void* const* d_in, const int* in_sizes, int n_in,
                              void* d_out, int out_size, void* d_ws, size_t ws_size,
                              hipStream_t stream) {
    const float* x1  = (const float*)d_in[0];
    // x2 (d_in[1]) is unused by the reference
    const int*   edge = (const int*)d_in[2];
    const float* W1  = (const float*)d_in[4];
    const float* as1 = (const float*)d_in[5];
    const float* ad1 = (const float*)d_in[6];
    const float* b1  = (const float*)d_in[7];
    const float* W2  = (const float*)d_in[8];
    const float* as2 = (const float*)d_in[9];
    const float* ad2 = (const float*)d_in[10];
    const float* b2  = (const float*)d_in[11];
    const float* W3  = (const float*)d_in[12];
    const float* as3 = (const float*)d_in[13];
    const float* ad3 = (const float*)d_in[14];
    const float* b3  = (const float*)d_in[15];
    const float* lw  = (const float*)d_in[16];
    float* out = (float*)d_out;

    const int n = in_sizes[0] / 10;     // 10000
    const int E = in_sizes[2] / 2;      // 320000

    // ---- workspace layout (16B aligned blocks) ----
    char* p = (char*)d_ws;
    int*   cnt     = (int*)p;   p += align16((size_t)n * 4);
    int*   rcnt    = (int*)p;   p += align16((size_t)n * 4);
    size_t zbytes  = (size_t)(p - (char*)d_ws);      // zero-init region ends here
    int*   fill    = (int*)p;   p += align16((size_t)n * 4);
    int*   rfill   = (int*)p;   p += align16((size_t)n * 4);
    int*   offsets = (int*)p;   p += align16((size_t)(n + 1) * 4);
    int*   roffsets= (int*)p;   p += align16((size_t)(n + 1) * 4);
    int*   csr     = (int*)p;   p += align16((size_t)(E + n) * 4);
    int*   rcsr    = (int*)p;   p += align16((size_t)E * 4);
    float* h1  = (float*)p; p += align16((size_t)n * 32 * 4);
    float* es1 = (float*)p; p += align16((size_t)n * 8 * 4);
    float* ed1 = (float*)p; p += align16((size_t)n * 8 * 4);
    float* x3  = (float*)p; p += align16((size_t)n * 32 * 4);
    float* h2  = (float*)p; p += align16((size_t)n * 16 * 4);
    float* es2 = (float*)p; p += align16((size_t)n * 4 * 4);
    float* ed2 = (float*)p; p += align16((size_t)n * 4 * 4);
    float* x4  = (float*)p; p += align16((size_t)n * 16 * 4);
    float* h3  = (float*)p; p += align16((size_t)n * 8 * 4);
    float* es3 = (float*)p; p += align16((size_t)n * 2 * 4);
    float* ed3 = (float*)p; p += align16((size_t)n * 2 * 4);
    float* x6  = (float*)p; p += align16((size_t)n * 8 * 4);

    hipMemsetAsync(d_ws, 0, zbytes, stream);   // just cnt + rcnt (80 KB)

    int ebl = (E + TPB - 1) / TPB;

    count_kernel<<<ebl, TPB, 0, stream>>>(edge, E, cnt, rcnt);
    scan_kernel<<<1, 1024, 0, stream>>>(cnt, rcnt, offsets, fill, csr, roffsets, rfill, n);
    scatter_kernel<<<ebl, TPB, 0, stream>>>(edge, E, fill, csr, rfill, rcsr);

    // layer 1: IN=10, H=8
    transform_kernel<10, 8><<<(n * 8 + TPB - 1) / TPB, TPB, 0, stream>>>(
        x1, W1, as1, ad1, n, h1, es1, ed1);
    aggregate_kernel<8><<<(n * 8 + 3) / 4, TPB, 0, stream>>>(
        offsets, csr, h1, es1, ed1, b1, n, x3);

    // layer 2: IN=32, H=4
    transform_kernel<32, 4><<<(n * 4 + TPB - 1) / TPB, TPB, 0, stream>>>(
        x3, W2, as2, ad2, n, h2, es2, ed2);
    aggregate_kernel<4><<<(n * 4 + 3) / 4, TPB, 0, stream>>>(
        offsets, csr, h2, es2, ed2, b2, n, x4);

    // layer 3: IN=16, H=2
    transform_kernel<16, 2><<<(n * 2 + TPB - 1) / TPB, TPB, 0, stream>>>(
        x4, W3, as3, ad3, n, h3, es3, ed3);
    aggregate_kernel<2><<<(n * 2 + 3) / 4, TPB, 0, stream>>>(
        offsets, csr, h3, es3, ed3, b3, n, x6);

    // fused scoring epilogue: one wave per node, shuffle-based dedup
    final_kernel<<<(n + 3) / 4, 256, 0, stream>>>(x6, roffsets, rcsr, x1, lw, out, n);
}